// Round 1
// baseline (161.161 us; speedup 1.0000x reference)
//
#include <hip/hip_runtime.h>
#include <math.h>

#define T_STEPS 256
#define BATCH   128
#define DIMD    512
#define HID     512
#define NROWS   (T_STEPS * BATCH)   // 32768

__device__ __forceinline__ float fast_sigmoid(float x) {
    return 1.0f / (1.0f + __expf(-x));
}
__device__ __forceinline__ float fast_tanh(float x) {
    x = fminf(fmaxf(x, -15.0f), 15.0f);
    float e = __expf(2.0f * x);
    return (e - 1.0f) / (e + 1.0f);
}

// ---------------------------------------------------------------------------
// Per-gate quantum constants: evolve columns 0 and 128 of U through the
// circuit, reduce to A, Bc, Bs (E(theta) = A + Bc cos + Bs sin) and sum(Wh).
// One block per gate, 256 threads (one per amplitude).
// ---------------------------------------------------------------------------
__global__ __launch_bounds__(256) void qconsts(
    const float* __restrict__ P0, const float* __restrict__ P1,
    const float* __restrict__ P2, const float* __restrict__ P3,
    const float* __restrict__ W0, const float* __restrict__ W1,
    const float* __restrict__ W2, const float* __restrict__ W3,
    float* __restrict__ gc)
{
    const float* P = (blockIdx.x == 0) ? P0 : (blockIdx.x == 1) ? P1
                   : (blockIdx.x == 2) ? P2 : P3;
    const float* W = (blockIdx.x == 0) ? W0 : (blockIdx.x == 1) ? W1
                   : (blockIdx.x == 2) ? W2 : W3;

    __shared__ float s0r[256], s0i[256], s1r[256], s1i[256];
    const int k = threadIdx.x;

    s0r[k] = (k == 0)   ? 1.0f : 0.0f;  s0i[k] = 0.0f;
    s1r[k] = (k == 128) ? 1.0f : 0.0f;  s1i[k] = 0.0f;
    __syncthreads();

    for (int l = 0; l < 2; ++l) {
        // 8 single-qubit rotations; qubit w lives on bit (7-w)
        for (int w = 0; w < 8; ++w) {
            const float phi = P[l * 24 + w * 3 + 0];
            const float th  = P[l * 24 + w * 3 + 1];
            const float om  = P[l * 24 + w * 3 + 2];
            float sh, ch;  __sincosf(0.5f * th, &sh, &ch);
            float sp, cp;  __sincosf(0.5f * (phi + om), &sp, &cp);
            float sm, cm;  __sincosf(0.5f * (phi - om), &sm, &cm);
            // m00 = e^{-i(phi+om)/2} c ; m01 = -e^{+i(phi-om)/2} s
            // m10 = e^{-i(phi-om)/2} s ; m11 = e^{+i(phi+om)/2} c
            const float m00r =  cp * ch, m00i = -sp * ch;
            const float m01r = -cm * sh, m01i = -sm * sh;
            const float m10r =  cm * sh, m10i = -sm * sh;
            const float m11r =  cp * ch, m11i =  sp * ch;

            const int shift = 7 - w;
            const int mask  = 1 << shift;
            const int bit   = (k >> shift) & 1;
            const int i0    = k & ~mask;
            const int i1    = k | mask;

            const float a0r = s0r[i0], a0i = s0i[i0];
            const float a1r = s0r[i1], a1i = s0i[i1];
            const float b0r = s1r[i0], b0i = s1i[i0];
            const float b1r = s1r[i1], b1i = s1i[i1];

            const float mr0 = bit ? m10r : m00r, mi0 = bit ? m10i : m00i;
            const float mr1 = bit ? m11r : m01r, mi1 = bit ? m11i : m01i;

            const float n0r = mr0 * a0r - mi0 * a0i + mr1 * a1r - mi1 * a1i;
            const float n0i = mr0 * a0i + mi0 * a0r + mr1 * a1i + mi1 * a1r;
            const float n1r = mr0 * b0r - mi0 * b0i + mr1 * b1r - mi1 * b1i;
            const float n1i = mr0 * b0i + mi0 * b0r + mr1 * b1i + mi1 * b1r;
            __syncthreads();          // all reads done
            s0r[k] = n0r; s0i[k] = n0i; s1r[k] = n1r; s1i[k] = n1i;
            __syncthreads();          // writes visible
        }
        // CNOT chain: final[i] = v[c0(c1(...c6(i)))]; cw flips target bit
        // (6-w) iff control bit (7-w) set.
        int src = k;
        for (int w = 6; w >= 0; --w) {
            const int cb = (src >> (7 - w)) & 1;
            src ^= cb << (6 - w);
        }
        const float n0r = s0r[src], n0i = s0i[src];
        const float n1r = s1r[src], n1i = s1i[src];
        __syncthreads();
        s0r[k] = n0r; s0i[k] = n0i; s1r[k] = n1r; s1i[k] = n1i;
        __syncthreads();
    }

    const float z = (k < 128) ? 1.0f : -1.0f;
    float t00 = z * (s0r[k] * s0r[k] + s0i[k] * s0i[k]);
    float t11 = z * (s1r[k] * s1r[k] + s1i[k] * s1i[k]);
    float t01 = z * (s0i[k] * s1r[k] - s0r[k] * s1i[k]);
    float tsw = W[512 + k] + W[768 + k];   // sum of W[0, 512:1024]

    const int lane = k & 63, wid = k >> 6;
    for (int off = 32; off; off >>= 1) {
        t00 += __shfl_xor(t00, off);
        t11 += __shfl_xor(t11, off);
        t01 += __shfl_xor(t01, off);
        tsw += __shfl_xor(tsw, off);
    }
    __shared__ float red[4][4];
    if (lane == 0) {
        red[wid][0] = t00; red[wid][1] = t11;
        red[wid][2] = t01; red[wid][3] = tsw;
    }
    __syncthreads();
    if (k == 0) {
        float S00 = 0, S11 = 0, S01 = 0, SW = 0;
        for (int wv = 0; wv < 4; ++wv) {
            S00 += red[wv][0]; S11 += red[wv][1];
            S01 += red[wv][2]; SW  += red[wv][3];
        }
        gc[blockIdx.x * 4 + 0] = 0.5f * (S00 + S11);   // A
        gc[blockIdx.x * 4 + 1] = 0.5f * (S00 - S11);   // Bc
        gc[blockIdx.x * 4 + 2] = -S01;                 // Bs
        gc[blockIdx.x * 4 + 3] = SW;                   // sum(Wh)
    }
}

// ---------------------------------------------------------------------------
// X[gate][t*B+b] = inputs[t,b,:] . W_gate[0, 0:512]. One wave per row.
// ---------------------------------------------------------------------------
__global__ __launch_bounds__(256) void gemv4(
    const float* __restrict__ x,
    const float* __restrict__ Wf, const float* __restrict__ Wi,
    const float* __restrict__ Wg, const float* __restrict__ Wo,
    float* __restrict__ X)
{
    const int lane = threadIdx.x & 63;
    const int wid  = threadIdx.x >> 6;
    const int row  = (blockIdx.x << 2) + wid;

    const float4* xr = (const float4*)(x + (size_t)row * DIMD);
    const float4 xa = xr[lane];
    const float4 xb = xr[lane + 64];

    const float4* wf = (const float4*)Wf;
    const float4* wi = (const float4*)Wi;
    const float4* wg = (const float4*)Wg;
    const float4* wo = (const float4*)Wo;
    const float4 fa = wf[lane], fb = wf[lane + 64];
    const float4 ia = wi[lane], ib = wi[lane + 64];
    const float4 ga = wg[lane], gb = wg[lane + 64];
    const float4 oa = wo[lane], ob = wo[lane + 64];

    float sf = xa.x * fa.x + xa.y * fa.y + xa.z * fa.z + xa.w * fa.w
             + xb.x * fb.x + xb.y * fb.y + xb.z * fb.z + xb.w * fb.w;
    float si = xa.x * ia.x + xa.y * ia.y + xa.z * ia.z + xa.w * ia.w
             + xb.x * ib.x + xb.y * ib.y + xb.z * ib.z + xb.w * ib.w;
    float sg = xa.x * ga.x + xa.y * ga.y + xa.z * ga.z + xa.w * ga.w
             + xb.x * gb.x + xb.y * gb.y + xb.z * gb.z + xb.w * gb.w;
    float so = xa.x * oa.x + xa.y * oa.y + xa.z * oa.z + xa.w * oa.w
             + xb.x * ob.x + xb.y * ob.y + xb.z * ob.z + xb.w * ob.w;

    for (int off = 32; off; off >>= 1) {
        sf += __shfl_xor(sf, off);
        si += __shfl_xor(si, off);
        sg += __shfl_xor(sg, off);
        so += __shfl_xor(so, off);
    }
    if (lane == 0) {
        X[row]             = sf;
        X[NROWS + row]     = si;
        X[2 * NROWS + row] = sg;
        X[3 * NROWS + row] = so;
    }
}

// ---------------------------------------------------------------------------
// Scalar LSTM recurrence: 128 independent chains (one per batch elem).
// ---------------------------------------------------------------------------
__global__ __launch_bounds__(64) void scan_k(
    const float* __restrict__ X, const float* __restrict__ gc,
    const float* __restrict__ bfp, const float* __restrict__ bip,
    const float* __restrict__ bgp, const float* __restrict__ bop,
    float* __restrict__ Hs, float* __restrict__ cfin)
{
    const int b = blockIdx.x * 64 + threadIdx.x;   // 0..127

    const float Af = gc[0],  Bcf = gc[1],  Bsf = gc[2],  swf = gc[3];
    const float Ai = gc[4],  Bci = gc[5],  Bsi = gc[6],  swi = gc[7];
    const float Ag = gc[8],  Bcg = gc[9],  Bsg = gc[10], swg = gc[11];
    const float Ao = gc[12], Bco = gc[13], Bso = gc[14], swo = gc[15];
    const float b0f = bfp[0], b0i = bip[0], b0g = bgp[0], b0o = bop[0];

    const float* Xf = X;
    const float* Xi = X + NROWS;
    const float* Xg = X + 2 * NROWS;
    const float* Xo = X + 3 * NROWS;

    float c = 0.0f, h = 0.0f;
    for (int t = 0; t < T_STEPS; ++t) {
        const int r = t * BATCH + b;
        const float thf = Xf[r] + h * swf + b0f;
        const float thi = Xi[r] + h * swi + b0i;
        const float thg = Xg[r] + h * swg + b0g;
        const float tho = Xo[r] + h * swo + b0o;

        float snf, csf; __sincosf(thf, &snf, &csf);
        float sni, csi; __sincosf(thi, &sni, &csi);
        float sng, csg; __sincosf(thg, &sng, &csg);
        float sno, cso; __sincosf(tho, &sno, &cso);

        const float Ef = Af + Bcf * csf + Bsf * snf;
        const float Ei = Ai + Bci * csi + Bsi * sni;
        const float Eg = Ag + Bcg * csg + Bsg * sng;
        const float Eo = Ao + Bco * cso + Bso * sno;

        const float fg = fast_sigmoid(Ef);
        const float ig = fast_sigmoid(Ei);
        const float gg = fast_tanh(Eg);
        const float og = fast_sigmoid(Eo);

        c = fg * c + ig * gg;
        h = og * fast_tanh(c);
        Hs[r] = h;
    }
    cfin[b] = c;
}

// ---------------------------------------------------------------------------
// Broadcast h/c scalars into the (T,B,H) outputs + hx + cx regions.
// ---------------------------------------------------------------------------
__global__ __launch_bounds__(256) void bcast(
    const float* __restrict__ Hs, const float* __restrict__ cfin,
    float4* __restrict__ out)
{
    const int i = blockIdx.x * 256 + threadIdx.x;  // float4 index, exact grid
    float v;
    if (i < 4194304) {                  // outputs: (t*B+b) = i>>7
        v = Hs[i >> 7];
    } else if (i < 4210688) {           // hx = Hs[255*B + b]
        v = Hs[32640 + ((i - 4194304) >> 7)];
    } else {                            // cx
        v = cfin[(i - 4210688) >> 7];
    }
    out[i] = make_float4(v, v, v, v);
}

extern "C" void kernel_launch(void* const* d_in, const int* in_sizes, int n_in,
                              void* d_out, int out_size, void* d_ws, size_t ws_size,
                              hipStream_t stream)
{
    const float* inp = (const float*)d_in[0];
    const float* Wf  = (const float*)d_in[1];
    const float* bfv = (const float*)d_in[2];
    const float* Pf  = (const float*)d_in[3];
    const float* Wi  = (const float*)d_in[4];
    const float* biv = (const float*)d_in[5];
    const float* Pi  = (const float*)d_in[6];
    const float* Wg  = (const float*)d_in[7];
    const float* bgv = (const float*)d_in[8];
    const float* Pg  = (const float*)d_in[9];
    const float* Wo  = (const float*)d_in[10];
    const float* bov = (const float*)d_in[11];
    const float* Po  = (const float*)d_in[12];

    float* ws   = (float*)d_ws;
    float* gc   = ws;                   // 16 floats
    float* X    = ws + 16;              // 4 * 32768
    float* Hs   = X + 4 * NROWS;        // 32768
    float* cfin = Hs + NROWS;           // 128

    qconsts<<<4, 256, 0, stream>>>(Pf, Pi, Pg, Po, Wf, Wi, Wg, Wo, gc);
    gemv4<<<NROWS / 4, 256, 0, stream>>>(inp, Wf, Wi, Wg, Wo, X);
    scan_k<<<2, 64, 0, stream>>>(X, gc, bfv, biv, bgv, bov, Hs, cfin);
    bcast<<<16512, 256, 0, stream>>>(Hs, cfin, (float4*)d_out);
}

// Round 2
// 144.749 us; speedup vs baseline: 1.1134x; 1.1134x over previous
//
#include <hip/hip_runtime.h>
#include <math.h>

#define T_STEPS 256
#define BATCH   128
#define DIMD    512
#define HID     512
#define NROWS   (T_STEPS * BATCH)   // 32768
#define PF      16                  // prefetch depth (register pipeline)

#define INV2PI  0.15915494309189535f
#define L2E     1.4426950408889634f

#if __has_builtin(__builtin_amdgcn_sinf)
#define HW_SIN(x) __builtin_amdgcn_sinf(x)   // sin(2*pi*x), x in revolutions
#define HW_COS(x) __builtin_amdgcn_cosf(x)
#else
__device__ __forceinline__ float HW_SIN(float x) { return __sinf(x * 6.283185307179586f); }
__device__ __forceinline__ float HW_COS(float x) { return __cosf(x * 6.283185307179586f); }
#endif

#if __has_builtin(__builtin_amdgcn_exp2f)
#define EXP2(x) __builtin_amdgcn_exp2f(x)
#else
#define EXP2(x) exp2f(x)
#endif

#if __has_builtin(__builtin_amdgcn_rcpf)
#define RCP(x) __builtin_amdgcn_rcpf(x)
#else
#define RCP(x) (1.0f / (x))
#endif

// ---------------------------------------------------------------------------
// Per-gate quantum constants: evolve columns 0 and 128 of U through the
// circuit, reduce to A, Bc, Bs (E(theta) = A + Bc cos + Bs sin) and sum(Wh).
// One block per gate, 256 threads (one per amplitude).
// ---------------------------------------------------------------------------
__global__ __launch_bounds__(256) void qconsts(
    const float* __restrict__ P0, const float* __restrict__ P1,
    const float* __restrict__ P2, const float* __restrict__ P3,
    const float* __restrict__ W0, const float* __restrict__ W1,
    const float* __restrict__ W2, const float* __restrict__ W3,
    float* __restrict__ gc)
{
    const float* P = (blockIdx.x == 0) ? P0 : (blockIdx.x == 1) ? P1
                   : (blockIdx.x == 2) ? P2 : P3;
    const float* W = (blockIdx.x == 0) ? W0 : (blockIdx.x == 1) ? W1
                   : (blockIdx.x == 2) ? W2 : W3;

    __shared__ float s0r[256], s0i[256], s1r[256], s1i[256];
    const int k = threadIdx.x;

    s0r[k] = (k == 0)   ? 1.0f : 0.0f;  s0i[k] = 0.0f;
    s1r[k] = (k == 128) ? 1.0f : 0.0f;  s1i[k] = 0.0f;
    __syncthreads();

    for (int l = 0; l < 2; ++l) {
        // 8 single-qubit rotations; qubit w lives on bit (7-w)
        for (int w = 0; w < 8; ++w) {
            const float phi = P[l * 24 + w * 3 + 0];
            const float th  = P[l * 24 + w * 3 + 1];
            const float om  = P[l * 24 + w * 3 + 2];
            float sh, ch;  __sincosf(0.5f * th, &sh, &ch);
            float sp, cp;  __sincosf(0.5f * (phi + om), &sp, &cp);
            float sm, cm;  __sincosf(0.5f * (phi - om), &sm, &cm);
            const float m00r =  cp * ch, m00i = -sp * ch;
            const float m01r = -cm * sh, m01i = -sm * sh;
            const float m10r =  cm * sh, m10i = -sm * sh;
            const float m11r =  cp * ch, m11i =  sp * ch;

            const int shift = 7 - w;
            const int mask  = 1 << shift;
            const int bit   = (k >> shift) & 1;
            const int i0    = k & ~mask;
            const int i1    = k | mask;

            const float a0r = s0r[i0], a0i = s0i[i0];
            const float a1r = s0r[i1], a1i = s0i[i1];
            const float b0r = s1r[i0], b0i = s1i[i0];
            const float b1r = s1r[i1], b1i = s1i[i1];

            const float mr0 = bit ? m10r : m00r, mi0 = bit ? m10i : m00i;
            const float mr1 = bit ? m11r : m01r, mi1 = bit ? m11i : m01i;

            const float n0r = mr0 * a0r - mi0 * a0i + mr1 * a1r - mi1 * a1i;
            const float n0i = mr0 * a0i + mi0 * a0r + mr1 * a1i + mi1 * a1r;
            const float n1r = mr0 * b0r - mi0 * b0i + mr1 * b1r - mi1 * b1i;
            const float n1i = mr0 * b0i + mi0 * b0r + mr1 * b1i + mi1 * b1r;
            __syncthreads();
            s0r[k] = n0r; s0i[k] = n0i; s1r[k] = n1r; s1i[k] = n1i;
            __syncthreads();
        }
        // CNOT chain permutation
        int src = k;
        for (int w = 6; w >= 0; --w) {
            const int cb = (src >> (7 - w)) & 1;
            src ^= cb << (6 - w);
        }
        const float n0r = s0r[src], n0i = s0i[src];
        const float n1r = s1r[src], n1i = s1i[src];
        __syncthreads();
        s0r[k] = n0r; s0i[k] = n0i; s1r[k] = n1r; s1i[k] = n1i;
        __syncthreads();
    }

    const float z = (k < 128) ? 1.0f : -1.0f;
    float t00 = z * (s0r[k] * s0r[k] + s0i[k] * s0i[k]);
    float t11 = z * (s1r[k] * s1r[k] + s1i[k] * s1i[k]);
    float t01 = z * (s0i[k] * s1r[k] - s0r[k] * s1i[k]);
    float tsw = W[512 + k] + W[768 + k];   // sum of W[0, 512:1024]

    const int lane = k & 63, wid = k >> 6;
    for (int off = 32; off; off >>= 1) {
        t00 += __shfl_xor(t00, off);
        t11 += __shfl_xor(t11, off);
        t01 += __shfl_xor(t01, off);
        tsw += __shfl_xor(tsw, off);
    }
    __shared__ float red[4][4];
    if (lane == 0) {
        red[wid][0] = t00; red[wid][1] = t11;
        red[wid][2] = t01; red[wid][3] = tsw;
    }
    __syncthreads();
    if (k == 0) {
        float S00 = 0, S11 = 0, S01 = 0, SW = 0;
        for (int wv = 0; wv < 4; ++wv) {
            S00 += red[wv][0]; S11 += red[wv][1];
            S01 += red[wv][2]; SW  += red[wv][3];
        }
        gc[blockIdx.x * 4 + 0] = 0.5f * (S00 + S11);   // A
        gc[blockIdx.x * 4 + 1] = 0.5f * (S00 - S11);   // Bc
        gc[blockIdx.x * 4 + 2] = -S01;                 // Bs
        gc[blockIdx.x * 4 + 3] = SW;                   // sum(Wh)
    }
}

// ---------------------------------------------------------------------------
// X[gate][t*B+b] = (inputs[t,b,:] . W_gate[0,0:512] + b0) / (2*pi)
// (revolutions, ready for v_sin/v_cos). One wave per row.
// ---------------------------------------------------------------------------
__global__ __launch_bounds__(256) void gemv4(
    const float* __restrict__ x,
    const float* __restrict__ Wf, const float* __restrict__ Wi,
    const float* __restrict__ Wg, const float* __restrict__ Wo,
    const float* __restrict__ bfp, const float* __restrict__ bip,
    const float* __restrict__ bgp, const float* __restrict__ bop,
    float* __restrict__ X)
{
    const int lane = threadIdx.x & 63;
    const int wid  = threadIdx.x >> 6;
    const int row  = (blockIdx.x << 2) + wid;

    const float4* xr = (const float4*)(x + (size_t)row * DIMD);
    const float4 xa = xr[lane];
    const float4 xb = xr[lane + 64];

    const float4* wf = (const float4*)Wf;
    const float4* wi = (const float4*)Wi;
    const float4* wg = (const float4*)Wg;
    const float4* wo = (const float4*)Wo;
    const float4 fa = wf[lane], fb = wf[lane + 64];
    const float4 ia = wi[lane], ib = wi[lane + 64];
    const float4 ga = wg[lane], gb = wg[lane + 64];
    const float4 oa = wo[lane], ob = wo[lane + 64];

    float sf = xa.x * fa.x + xa.y * fa.y + xa.z * fa.z + xa.w * fa.w
             + xb.x * fb.x + xb.y * fb.y + xb.z * fb.z + xb.w * fb.w;
    float si = xa.x * ia.x + xa.y * ia.y + xa.z * ia.z + xa.w * ia.w
             + xb.x * ib.x + xb.y * ib.y + xb.z * ib.z + xb.w * ib.w;
    float sg = xa.x * ga.x + xa.y * ga.y + xa.z * ga.z + xa.w * ga.w
             + xb.x * gb.x + xb.y * gb.y + xb.z * gb.z + xb.w * gb.w;
    float so = xa.x * oa.x + xa.y * oa.y + xa.z * oa.z + xa.w * oa.w
             + xb.x * ob.x + xb.y * ob.y + xb.z * ob.z + xb.w * ob.w;

    for (int off = 32; off; off >>= 1) {
        sf += __shfl_xor(sf, off);
        si += __shfl_xor(si, off);
        sg += __shfl_xor(sg, off);
        so += __shfl_xor(so, off);
    }
    if (lane == 0) {
        X[row]             = (sf + bfp[0]) * INV2PI;
        X[NROWS + row]     = (si + bip[0]) * INV2PI;
        X[2 * NROWS + row] = (sg + bgp[0]) * INV2PI;
        X[3 * NROWS + row] = (so + bop[0]) * INV2PI;
    }
}

// ---------------------------------------------------------------------------
// Scalar LSTM recurrence: 128 independent chains (one per batch elem).
// PF-deep register prefetch pipeline takes X loads off the dependent chain.
// ---------------------------------------------------------------------------
__global__ __launch_bounds__(64) void scan_k(
    const float* __restrict__ X, const float* __restrict__ gc,
    float* __restrict__ Hs, float* __restrict__ cfin)
{
    const int b = blockIdx.x * 64 + threadIdx.x;   // 0..127

    // Prescaled constants: sigmoid gates get -log2(e)*E (so f = rcp(1+exp2)),
    // tanh gate gets 2*log2(e)*E. sw folded to revolutions.
    const float swf = gc[3]  * INV2PI;
    const float swi = gc[7]  * INV2PI;
    const float swg = gc[11] * INV2PI;
    const float swo = gc[15] * INV2PI;
    const float Af = -L2E * gc[0],  Bcf = -L2E * gc[1],  Bsf = -L2E * gc[2];
    const float Ai = -L2E * gc[4],  Bci = -L2E * gc[5],  Bsi = -L2E * gc[6];
    const float Ag = 2.0f * L2E * gc[8], Bcg = 2.0f * L2E * gc[9], Bsg = 2.0f * L2E * gc[10];
    const float Ao = -L2E * gc[12], Bco = -L2E * gc[13], Bso = -L2E * gc[14];

    const float* Xf = X;
    const float* Xi = X + NROWS;
    const float* Xg = X + 2 * NROWS;
    const float* Xo = X + 3 * NROWS;

    float pf[PF], pi_[PF], pg[PF], po[PF];
#pragma unroll
    for (int j = 0; j < PF; ++j) {
        const int r = j * BATCH + b;
        pf[j] = Xf[r]; pi_[j] = Xi[r]; pg[j] = Xg[r]; po[j] = Xo[r];
    }

    float c = 0.0f, h = 0.0f;
    for (int tb = 0; tb < T_STEPS; tb += PF) {
#pragma unroll
        for (int j = 0; j < PF; ++j) {
            const int t = tb + j;
            const float xf = pf[j], xi = pi_[j], xg = pg[j], xo = po[j];
            // refill this slot PF steps ahead (off the dependent chain)
            if (t + PF < T_STEPS) {
                const int r = (t + PF) * BATCH + b;
                pf[j] = Xf[r]; pi_[j] = Xi[r]; pg[j] = Xg[r]; po[j] = Xo[r];
            }

            const float thf = fmaf(h, swf, xf);   // revolutions
            const float thi = fmaf(h, swi, xi);
            const float thg = fmaf(h, swg, xg);
            const float tho = fmaf(h, swo, xo);

            const float snf = HW_SIN(thf), csf = HW_COS(thf);
            const float sni = HW_SIN(thi), csi = HW_COS(thi);
            const float sng = HW_SIN(thg), csg = HW_COS(thg);
            const float sno = HW_SIN(tho), cso = HW_COS(tho);

            const float Ef = fmaf(Bcf, csf, fmaf(Bsf, snf, Af));  // = -L2E*E
            const float Ei = fmaf(Bci, csi, fmaf(Bsi, sni, Ai));
            const float Eg = fmaf(Bcg, csg, fmaf(Bsg, sng, Ag));  // = 2*L2E*E
            const float Eo = fmaf(Bco, cso, fmaf(Bso, sno, Ao));

            const float fg = RCP(1.0f + EXP2(Ef));
            const float ig = RCP(1.0f + EXP2(Ei));
            const float og = RCP(1.0f + EXP2(Eo));
            const float gg = 1.0f - 2.0f * RCP(EXP2(Eg) + 1.0f); // tanh

            c = fmaf(fg, c, ig * gg);
            const float ec = EXP2(c * (2.0f * L2E));
            h = og * (1.0f - 2.0f * RCP(ec + 1.0f));             // o*tanh(c)
            Hs[t * BATCH + b] = h;
        }
    }
    cfin[b] = c;
}

// ---------------------------------------------------------------------------
// Broadcast h/c scalars into the (T,B,H) outputs + hx + cx regions.
// ---------------------------------------------------------------------------
__global__ __launch_bounds__(256) void bcast(
    const float* __restrict__ Hs, const float* __restrict__ cfin,
    float4* __restrict__ out)
{
    const int i = blockIdx.x * 256 + threadIdx.x;  // float4 index, exact grid
    float v;
    if (i < 4194304) {                  // outputs: (t*B+b) = i>>7
        v = Hs[i >> 7];
    } else if (i < 4210688) {           // hx = Hs[255*B + b]
        v = Hs[32640 + ((i - 4194304) >> 7)];
    } else {                            // cx
        v = cfin[(i - 4210688) >> 7];
    }
    out[i] = make_float4(v, v, v, v);
}

extern "C" void kernel_launch(void* const* d_in, const int* in_sizes, int n_in,
                              void* d_out, int out_size, void* d_ws, size_t ws_size,
                              hipStream_t stream)
{
    const float* inp = (const float*)d_in[0];
    const float* Wf  = (const float*)d_in[1];
    const float* bfv = (const float*)d_in[2];
    const float* Pf  = (const float*)d_in[3];
    const float* Wi  = (const float*)d_in[4];
    const float* biv = (const float*)d_in[5];
    const float* Pi  = (const float*)d_in[6];
    const float* Wg  = (const float*)d_in[7];
    const float* bgv = (const float*)d_in[8];
    const float* Pg  = (const float*)d_in[9];
    const float* Wo  = (const float*)d_in[10];
    const float* bov = (const float*)d_in[11];
    const float* Po  = (const float*)d_in[12];

    float* ws   = (float*)d_ws;
    float* gc   = ws;                   // 16 floats
    float* X    = ws + 16;              // 4 * 32768
    float* Hs   = X + 4 * NROWS;        // 32768
    float* cfin = Hs + NROWS;           // 128

    qconsts<<<4, 256, 0, stream>>>(Pf, Pi, Pg, Po, Wf, Wi, Wg, Wo, gc);
    gemv4<<<NROWS / 4, 256, 0, stream>>>(inp, Wf, Wi, Wg, Wo, bfv, biv, bgv, bov, X);
    scan_k<<<2, 64, 0, stream>>>(X, gc, Hs, cfin);
    bcast<<<16512, 256, 0, stream>>>(Hs, cfin, (float4*)d_out);
}

// Round 3
// 68.525 us; speedup vs baseline: 2.3519x; 2.1124x over previous
//
#include <hip/hip_runtime.h>
#include <math.h>

#define T_STEPS 256
#define BATCH   128
#define DIMD    512
#define HID     512
#define NROWS   (T_STEPS * BATCH)   // 32768
#define PF      16                  // prefetch depth (register pipeline)

#define INV2PI  0.15915494309189535f
#define L2E     1.4426950408889634f

#if __has_builtin(__builtin_amdgcn_sinf)
#define HW_SIN(x) __builtin_amdgcn_sinf(x)   // sin(2*pi*x), x in revolutions
#define HW_COS(x) __builtin_amdgcn_cosf(x)
#else
__device__ __forceinline__ float HW_SIN(float x) { return __sinf(x * 6.283185307179586f); }
__device__ __forceinline__ float HW_COS(float x) { return __cosf(x * 6.283185307179586f); }
#endif

#if __has_builtin(__builtin_amdgcn_exp2f)
#define EXP2(x) __builtin_amdgcn_exp2f(x)
#else
#define EXP2(x) exp2f(x)
#endif

#if __has_builtin(__builtin_amdgcn_rcpf)
#define RCP(x) __builtin_amdgcn_rcpf(x)
#else
#define RCP(x) (1.0f / (x))
#endif

// ---------------------------------------------------------------------------
// Per-gate quantum constants: evolve columns 0 and 128 of U through the
// circuit, reduce to A, Bc, Bs (E(theta) = A + Bc cos + Bs sin) and sum(Wh).
// One block per gate, 256 threads (one per amplitude).
// ---------------------------------------------------------------------------
__global__ __launch_bounds__(256) void qconsts(
    const float* __restrict__ P0, const float* __restrict__ P1,
    const float* __restrict__ P2, const float* __restrict__ P3,
    const float* __restrict__ W0, const float* __restrict__ W1,
    const float* __restrict__ W2, const float* __restrict__ W3,
    float* __restrict__ gc)
{
    const float* P = (blockIdx.x == 0) ? P0 : (blockIdx.x == 1) ? P1
                   : (blockIdx.x == 2) ? P2 : P3;
    const float* W = (blockIdx.x == 0) ? W0 : (blockIdx.x == 1) ? W1
                   : (blockIdx.x == 2) ? W2 : W3;

    __shared__ float s0r[256], s0i[256], s1r[256], s1i[256];
    const int k = threadIdx.x;

    s0r[k] = (k == 0)   ? 1.0f : 0.0f;  s0i[k] = 0.0f;
    s1r[k] = (k == 128) ? 1.0f : 0.0f;  s1i[k] = 0.0f;
    __syncthreads();

    for (int l = 0; l < 2; ++l) {
        // 8 single-qubit rotations; qubit w lives on bit (7-w)
        for (int w = 0; w < 8; ++w) {
            const float phi = P[l * 24 + w * 3 + 0];
            const float th  = P[l * 24 + w * 3 + 1];
            const float om  = P[l * 24 + w * 3 + 2];
            float sh, ch;  __sincosf(0.5f * th, &sh, &ch);
            float sp, cp;  __sincosf(0.5f * (phi + om), &sp, &cp);
            float sm, cm;  __sincosf(0.5f * (phi - om), &sm, &cm);
            const float m00r =  cp * ch, m00i = -sp * ch;
            const float m01r = -cm * sh, m01i = -sm * sh;
            const float m10r =  cm * sh, m10i = -sm * sh;
            const float m11r =  cp * ch, m11i =  sp * ch;

            const int shift = 7 - w;
            const int mask  = 1 << shift;
            const int bit   = (k >> shift) & 1;
            const int i0    = k & ~mask;
            const int i1    = k | mask;

            const float a0r = s0r[i0], a0i = s0i[i0];
            const float a1r = s0r[i1], a1i = s0i[i1];
            const float b0r = s1r[i0], b0i = s1i[i0];
            const float b1r = s1r[i1], b1i = s1i[i1];

            const float mr0 = bit ? m10r : m00r, mi0 = bit ? m10i : m00i;
            const float mr1 = bit ? m11r : m01r, mi1 = bit ? m11i : m01i;

            const float n0r = mr0 * a0r - mi0 * a0i + mr1 * a1r - mi1 * a1i;
            const float n0i = mr0 * a0i + mi0 * a0r + mr1 * a1i + mi1 * a1r;
            const float n1r = mr0 * b0r - mi0 * b0i + mr1 * b1r - mi1 * b1i;
            const float n1i = mr0 * b0i + mi0 * b0r + mr1 * b1i + mi1 * b1r;
            __syncthreads();
            s0r[k] = n0r; s0i[k] = n0i; s1r[k] = n1r; s1i[k] = n1i;
            __syncthreads();
        }
        // CNOT chain permutation
        int src = k;
        for (int w = 6; w >= 0; --w) {
            const int cb = (src >> (7 - w)) & 1;
            src ^= cb << (6 - w);
        }
        const float n0r = s0r[src], n0i = s0i[src];
        const float n1r = s1r[src], n1i = s1i[src];
        __syncthreads();
        s0r[k] = n0r; s0i[k] = n0i; s1r[k] = n1r; s1i[k] = n1i;
        __syncthreads();
    }

    const float z = (k < 128) ? 1.0f : -1.0f;
    float t00 = z * (s0r[k] * s0r[k] + s0i[k] * s0i[k]);
    float t11 = z * (s1r[k] * s1r[k] + s1i[k] * s1i[k]);
    float t01 = z * (s0i[k] * s1r[k] - s0r[k] * s1i[k]);
    float tsw = W[512 + k] + W[768 + k];   // sum of W[0, 512:1024]

    const int lane = k & 63, wid = k >> 6;
    for (int off = 32; off; off >>= 1) {
        t00 += __shfl_xor(t00, off);
        t11 += __shfl_xor(t11, off);
        t01 += __shfl_xor(t01, off);
        tsw += __shfl_xor(tsw, off);
    }
    __shared__ float red[4][4];
    if (lane == 0) {
        red[wid][0] = t00; red[wid][1] = t11;
        red[wid][2] = t01; red[wid][3] = tsw;
    }
    __syncthreads();
    if (k == 0) {
        float S00 = 0, S11 = 0, S01 = 0, SW = 0;
        for (int wv = 0; wv < 4; ++wv) {
            S00 += red[wv][0]; S11 += red[wv][1];
            S01 += red[wv][2]; SW  += red[wv][3];
        }
        gc[blockIdx.x * 4 + 0] = 0.5f * (S00 + S11);   // A
        gc[blockIdx.x * 4 + 1] = 0.5f * (S00 - S11);   // Bc
        gc[blockIdx.x * 4 + 2] = -S01;                 // Bs
        gc[blockIdx.x * 4 + 3] = SW;                   // sum(Wh)
    }
}

// ---------------------------------------------------------------------------
// X4[t*B+b] = float4(f,i,g,o) pre-activations in revolutions (bias folded).
// One wave per row.
// ---------------------------------------------------------------------------
__global__ __launch_bounds__(256) void gemv4(
    const float* __restrict__ x,
    const float* __restrict__ Wf, const float* __restrict__ Wi,
    const float* __restrict__ Wg, const float* __restrict__ Wo,
    const float* __restrict__ bfp, const float* __restrict__ bip,
    const float* __restrict__ bgp, const float* __restrict__ bop,
    float4* __restrict__ X4)
{
    const int lane = threadIdx.x & 63;
    const int wid  = threadIdx.x >> 6;
    const int row  = (blockIdx.x << 2) + wid;

    const float4* xr = (const float4*)(x + (size_t)row * DIMD);
    const float4 xa = xr[lane];
    const float4 xb = xr[lane + 64];

    const float4* wf = (const float4*)Wf;
    const float4* wi = (const float4*)Wi;
    const float4* wg = (const float4*)Wg;
    const float4* wo = (const float4*)Wo;
    const float4 fa = wf[lane], fb = wf[lane + 64];
    const float4 ia = wi[lane], ib = wi[lane + 64];
    const float4 ga = wg[lane], gb = wg[lane + 64];
    const float4 oa = wo[lane], ob = wo[lane + 64];

    float sf = xa.x * fa.x + xa.y * fa.y + xa.z * fa.z + xa.w * fa.w
             + xb.x * fb.x + xb.y * fb.y + xb.z * fb.z + xb.w * fb.w;
    float si = xa.x * ia.x + xa.y * ia.y + xa.z * ia.z + xa.w * ia.w
             + xb.x * ib.x + xb.y * ib.y + xb.z * ib.z + xb.w * ib.w;
    float sg = xa.x * ga.x + xa.y * ga.y + xa.z * ga.z + xa.w * ga.w
             + xb.x * gb.x + xb.y * gb.y + xb.z * gb.z + xb.w * gb.w;
    float so = xa.x * oa.x + xa.y * oa.y + xa.z * oa.z + xa.w * oa.w
             + xb.x * ob.x + xb.y * ob.y + xb.z * ob.z + xb.w * ob.w;

    for (int off = 32; off; off >>= 1) {
        sf += __shfl_xor(sf, off);
        si += __shfl_xor(si, off);
        sg += __shfl_xor(sg, off);
        so += __shfl_xor(so, off);
    }
    if (lane == 0) {
        X4[row] = make_float4((sf + bfp[0]) * INV2PI,
                              (si + bip[0]) * INV2PI,
                              (sg + bgp[0]) * INV2PI,
                              (so + bop[0]) * INV2PI);
    }
}

// ---------------------------------------------------------------------------
// Scalar LSTM recurrence: 128 independent chains (one per batch elem).
// Branchless PF-deep register prefetch (X4 padded by PF*BATCH entries) so the
// compiler can emit counted vmcnt waits — loads stay off the dependent chain.
// ---------------------------------------------------------------------------
__global__ __launch_bounds__(64) void scan_k(
    const float4* __restrict__ X4, const float* __restrict__ gc,
    float* __restrict__ Hs, float* __restrict__ cfin)
{
    const int b = blockIdx.x * 64 + threadIdx.x;   // 0..127

    // Prescaled constants: sigmoid gates get -log2(e)*E (so f = rcp(1+exp2)),
    // tanh gate gets 2*log2(e)*E. sw folded to revolutions.
    const float swf = gc[3]  * INV2PI;
    const float swi = gc[7]  * INV2PI;
    const float swg = gc[11] * INV2PI;
    const float swo = gc[15] * INV2PI;
    const float Af = -L2E * gc[0],  Bcf = -L2E * gc[1],  Bsf = -L2E * gc[2];
    const float Ai = -L2E * gc[4],  Bci = -L2E * gc[5],  Bsi = -L2E * gc[6];
    const float Ag = 2.0f * L2E * gc[8], Bcg = 2.0f * L2E * gc[9], Bsg = 2.0f * L2E * gc[10];
    const float Ao = -L2E * gc[12], Bco = -L2E * gc[13], Bso = -L2E * gc[14];

    float4 p[PF];
#pragma unroll
    for (int j = 0; j < PF; ++j) p[j] = X4[j * BATCH + b];

    float c = 0.0f, h = 0.0f;
    for (int tb = 0; tb < T_STEPS; tb += PF) {
#pragma unroll
        for (int j = 0; j < PF; ++j) {
            const int t = tb + j;
            const float4 xv = p[j];
            // branchless refill PF steps ahead (padded region beyond t=255)
            p[j] = X4[(t + PF) * BATCH + b];

            const float thf = fmaf(h, swf, xv.x);   // revolutions
            const float thi = fmaf(h, swi, xv.y);
            const float thg = fmaf(h, swg, xv.z);
            const float tho = fmaf(h, swo, xv.w);

            const float snf = HW_SIN(thf), csf = HW_COS(thf);
            const float sni = HW_SIN(thi), csi = HW_COS(thi);
            const float sng = HW_SIN(thg), csg = HW_COS(thg);
            const float sno = HW_SIN(tho), cso = HW_COS(tho);

            const float Ef = fmaf(Bcf, csf, fmaf(Bsf, snf, Af));  // = -L2E*E
            const float Ei = fmaf(Bci, csi, fmaf(Bsi, sni, Ai));
            const float Eg = fmaf(Bcg, csg, fmaf(Bsg, sng, Ag));  // = 2*L2E*E
            const float Eo = fmaf(Bco, cso, fmaf(Bso, sno, Ao));

            const float fg = RCP(1.0f + EXP2(Ef));
            const float ig = RCP(1.0f + EXP2(Ei));
            const float og = RCP(1.0f + EXP2(Eo));
            const float gg = 1.0f - 2.0f * RCP(EXP2(Eg) + 1.0f); // tanh

            c = fmaf(fg, c, ig * gg);
            const float ec = EXP2(c * (2.0f * L2E));
            h = og * (1.0f - 2.0f * RCP(ec + 1.0f));             // o*tanh(c)
            Hs[t * BATCH + b] = h;
        }
    }
    cfin[b] = c;
}

// ---------------------------------------------------------------------------
// Broadcast h/c scalars into the (T,B,H) outputs + hx + cx regions.
// ---------------------------------------------------------------------------
__global__ __launch_bounds__(256) void bcast(
    const float* __restrict__ Hs, const float* __restrict__ cfin,
    float4* __restrict__ out)
{
    const int i = blockIdx.x * 256 + threadIdx.x;  // float4 index, exact grid
    float v;
    if (i < 4194304) {                  // outputs: (t*B+b) = i>>7
        v = Hs[i >> 7];
    } else if (i < 4210688) {           // hx = Hs[255*B + b]
        v = Hs[32640 + ((i - 4194304) >> 7)];
    } else {                            // cx
        v = cfin[(i - 4210688) >> 7];
    }
    out[i] = make_float4(v, v, v, v);
}

extern "C" void kernel_launch(void* const* d_in, const int* in_sizes, int n_in,
                              void* d_out, int out_size, void* d_ws, size_t ws_size,
                              hipStream_t stream)
{
    const float* inp = (const float*)d_in[0];
    const float* Wf  = (const float*)d_in[1];
    const float* bfv = (const float*)d_in[2];
    const float* Pf  = (const float*)d_in[3];
    const float* Wi  = (const float*)d_in[4];
    const float* biv = (const float*)d_in[5];
    const float* Pi  = (const float*)d_in[6];
    const float* Wg  = (const float*)d_in[7];
    const float* bgv = (const float*)d_in[8];
    const float* Pg  = (const float*)d_in[9];
    const float* Wo  = (const float*)d_in[10];
    const float* bov = (const float*)d_in[11];
    const float* Po  = (const float*)d_in[12];

    float* ws   = (float*)d_ws;
    float* gc   = ws;                        // 16 floats
    float4* X4  = (float4*)(ws + 16);        // (NROWS + PF*BATCH) float4s
    float* Hs   = (float*)(X4 + NROWS + PF * BATCH);
    float* cfin = Hs + NROWS;                // 128

    qconsts<<<4, 256, 0, stream>>>(Pf, Pi, Pg, Po, Wf, Wi, Wg, Wo, gc);
    gemv4<<<NROWS / 4, 256, 0, stream>>>(inp, Wf, Wi, Wg, Wo, bfv, biv, bgv, bov, X4);
    scan_k<<<2, 64, 0, stream>>>(X4, gc, Hs, cfin);
    bcast<<<16512, 256, 0, stream>>>(Hs, cfin, (float4*)d_out);
}